// Round 12
// baseline (2356.174 us; speedup 1.0000x reference)
//
#include <hip/hip_runtime.h>
#include <math.h>

#define NWG 256
#define TPB 1024

static constexpr int Bc=128, Ic=256, Hc=512, NCc=16, Tc=24, Mc=14;
static constexpr int Y_SZ  = Bc*NCc*Tc;     // 49152
static constexpr int P_OFF = Y_SZ;
static constexpr int N_OFF = Y_SZ + Bc;

// ws layout (floats): hbuf[2][512][128], stc[2][512][128], hpp[2][64][128]
static constexpr int HSZ    = Hc*Bc;              // 65536
static constexpr int HB_OFF = 0;
static constexpr int SC_OFF = 2*HSZ;
static constexpr int HP_OFF = 4*HSZ;
static constexpr int HPSZ   = 64*128;             // 8192 per parity
// total = 278528 floats = 1.06 MiB (< proven 1.375)

typedef float f4v __attribute__((ext_vector_type(4)));

// Hierarchical barrier (r11-proven): 16 groups x 16 blocks, monotonic watermarks.
__device__ __align__(64) unsigned g_bcnt[16][16];
__device__ __align__(64) unsigned g_bgen[16][16];
__device__ __align__(64) unsigned g_brc[16];
__device__ __align__(64) unsigned g_brg[16];

__device__ __forceinline__ float sigm(float v){ return 1.0f/(1.0f+expf(-v)); }

// PRODUCER: system-scope write-through stores (sc0 sc1) -> coherent at IF.
__device__ __forceinline__ void gstore(float* p, float v){
  __hip_atomic_store(p, v, __ATOMIC_RELAXED, __HIP_MEMORY_SCOPE_SYSTEM);
}

__device__ __forceinline__ void gsync(int w){
  __syncthreads();
  if (threadIdx.x == 0) {
    asm volatile("" ::: "memory");
    const int g = w >> 4;
    unsigned prev = __hip_atomic_fetch_add(&g_bcnt[g][0], 1u, __ATOMIC_RELAXED, __HIP_MEMORY_SCOPE_SYSTEM);
    unsigned ep   = prev >> 4;
    if ((prev & 15u) == 15u) {
      unsigned rprev = __hip_atomic_fetch_add(&g_brc[0], 1u, __ATOMIC_RELAXED, __HIP_MEMORY_SCOPE_SYSTEM);
      if ((rprev & 15u) == 15u) {
        __hip_atomic_store(&g_brg[0], (rprev >> 4) + 1u, __ATOMIC_RELEASE, __HIP_MEMORY_SCOPE_SYSTEM);
      } else {
        while ((int)(__hip_atomic_load(&g_brg[0], __ATOMIC_RELAXED, __HIP_MEMORY_SCOPE_SYSTEM) - (ep + 1u)) < 0)
          __builtin_amdgcn_s_sleep(1);
      }
      __hip_atomic_store(&g_bgen[g][0], ep + 1u, __ATOMIC_RELEASE, __HIP_MEMORY_SCOPE_SYSTEM);
    } else {
      while ((int)(__hip_atomic_load(&g_bgen[g][0], __ATOMIC_RELAXED, __HIP_MEMORY_SCOPE_SYSTEM) - (ep + 1u)) < 0)
        __builtin_amdgcn_s_sleep(1);
    }
    asm volatile("" ::: "memory");
  }
  __syncthreads();
}

// 16 FMAs on a 4-row x 4-batch register tile from one h f4 + 4 weight scalars
#define TILE_FMA(s0,s1,s2,s3,hv)                                              \
  a0.x=fmaf(s0,hv.x,a0.x); a0.y=fmaf(s0,hv.y,a0.y);                           \
  a0.z=fmaf(s0,hv.z,a0.z); a0.w=fmaf(s0,hv.w,a0.w);                           \
  a1.x=fmaf(s1,hv.x,a1.x); a1.y=fmaf(s1,hv.y,a1.y);                           \
  a1.z=fmaf(s1,hv.z,a1.z); a1.w=fmaf(s1,hv.w,a1.w);                           \
  a2.x=fmaf(s2,hv.x,a2.x); a2.y=fmaf(s2,hv.y,a2.y);                           \
  a2.z=fmaf(s2,hv.z,a2.z); a2.w=fmaf(s2,hv.w,a2.w);                           \
  a3.x=fmaf(s3,hv.x,a3.x); a3.y=fmaf(s3,hv.y,a3.y);                           \
  a3.z=fmaf(s3,hv.z,a3.z); a3.w=fmaf(s3,hv.w,a3.w);

// write the tile to part[q][r][b] (f4 over b)
#define WRITE_PART(q)                                                         \
  *(f4v*)&part[(q)*1024 + (rgrp*4+0)*32 + b4*4] = a0;                         \
  *(f4v*)&part[(q)*1024 + (rgrp*4+1)*32 + b4*4] = a1;                         \
  *(f4v*)&part[(q)*1024 + (rgrp*4+2)*32 + b4*4] = a2;                         \
  *(f4v*)&part[(q)*1024 + (rgrp*4+3)*32 + b4*4] = a3;

// 2-pass cross-wave reduce (fixed order, deterministic): part -> sums[32r][32b]
#define REDUCE_TO_SUMS                                                        \
  {                                                                           \
    if (kg >= 8) { WRITE_PART(kg-8) }                                         \
    __syncthreads();                                                          \
    float racc = 0.f;                                                         \
    _Pragma("unroll")                                                         \
    for (int q=0;q<8;++q) racc += part[q*1024 + rr*32 + bb];                  \
    __syncthreads();                                                          \
    if (kg < 8) { WRITE_PART(kg) }                                            \
    __syncthreads();                                                          \
    _Pragma("unroll")                                                         \
    for (int q=0;q<8;++q) racc += part[q*1024 + rr*32 + bb];                  \
    sums[rr*32 + bb] = racc;                                                  \
    __syncthreads();                                                          \
  }

__global__ __launch_bounds__(TPB, 1) void act_lstm_kernel(
    const float* __restrict__ x,   const float* __restrict__ Wih,
    const float* __restrict__ Whh, const float* __restrict__ bih,
    const float* __restrict__ bhh, const float* __restrict__ hw,
    const float* __restrict__ hbp, const float* __restrict__ dw,
    const float* __restrict__ db,  float* __restrict__ out,
    float* __restrict__ ws)
{
  const int w    = blockIdx.x;
  const int tid  = threadIdx.x;
  const int lane = tid & 63;
  const int wid  = __builtin_amdgcn_readfirstlane(tid >> 6); // 0..15 = k/i-chunk
  const int jg   = w >> 2;           // j-group: j in [jg*8, +8)
  const int bgr  = w & 3;            // batch-group: b in [bgr*32, +32)
  const int rgrp = lane >> 3;        // 4-row group (8 x 4 = 32 rows)
  const int b4   = lane & 7;         // 4-batch group (8 x 4 = 32 b)
  const int kg   = wid;
  const int rr   = tid >> 5, bb = tid & 31;     // reducer: (row, b)
  const bool iscell = (tid < 256);
  const int jloc = tid >> 5, bl = tid & 31;     // cell: 8 j x 32 b
  const int jglob = jg*8 + jloc, bglob = bgr*32 + bl;

  float* hbuf = ws + HB_OFF;
  float* stc  = ws + SC_OFF;
  float* hpp  = ws + HP_OFF;

  __shared__ float h_lds[16384];   // [k 512][b 32]  64 KB
  __shared__ float x_lds[8192];    // [i 256][b 32]  32 KB
  __shared__ float part[8192];     // [q 8][r 32][b 32]; aliased as hq in phase B
  __shared__ float sums[1024];     // [r 32][b 32]
  __shared__ float hp[256];
  __shared__ float hq2[512];
  __shared__ float pnl[128];
  __shared__ float pmh[128];
  __shared__ unsigned ldsu[2];
  float* hq = part;

  // weight row pointers (4 rows per lane), L2-resident slices
  const f4v* whr[4]; const f4v* wxr[4];
  #pragma unroll
  for (int i=0;i<4;++i){
    int r = rgrp*4+i;
    int grow = (r>>3)*512 + jg*8 + (r&7);
    whr[i] = (const f4v*)(Whh + grow*Hc) + kg*8;   // 8 f4 = 32 k
    wxr[i] = (const f4v*)(Wih + grow*Ic) + kg*4;   // 4 f4 = 16 i
  }
  float bsum[4] = {0,0,0,0};
  float hwj = 0.f;
  if (iscell){
    #pragma unroll
    for (int g=0;g<4;++g) bsum[g] = bih[g*512 + jglob] + bhh[g*512 + jglob];
    hwj = hw[jglob];
  }
  const float hb0 = hbp[0];

  // persistent state
  float c=0.f, st_run=0.f, ct_run=0.f, prev_pm=0.f;                 // cell
  float cumw=0.f, prevw=0.f, ntfw=0.f, rtvw=0.f, psumw=0.f;         // tracker (wid<2)
  bool  ntsetw=false;
  int   gt=0, lastpar=0;
  float xg[4] = {0,0,0,0};

  for (int t=0; t<Tc; ++t){
    for (int mm=0;; ++mm){
      const bool do_h = !(mm==0 && t==0);

      // ---- stage h (volatile f4, IF-coherent) and x ----
      if (mm == 0){
        #pragma unroll
        for (int u=0;u<8;++u){
          int idx = u*1024 + tid, i = idx>>5, b2 = idx&31;
          x_lds[idx] = x[(bgr*32 + b2)*(Ic*Tc) + i*Tc + t];
        }
        if (t > 0){
          const float* src = stc + lastpar*HSZ;
          #pragma unroll
          for (int u=0;u<4;++u){
            int f = u*1024 + tid, k = f>>3, q = f&7;
            f4v hv = *(const volatile f4v*)(src + k*128 + bgr*32 + q*4);
            *(f4v*)&h_lds[k*32 + q*4] = hv;
          }
        }
      } else {
        const float* src = hbuf + ((gt-1)&1)*HSZ;
        #pragma unroll
        for (int u=0;u<4;++u){
          int f = u*1024 + tid, k = f>>3, q = f&7;
          f4v hv = *(const volatile f4v*)(src + k*128 + bgr*32 + q*4);
          *(f4v*)&h_lds[k*32 + q*4] = hv;
        }
      }
      __syncthreads();

      // ---- x-GEMV + decoder Y[t-1] at mm==0 ----
      if (mm == 0){
        f4v a0={0,0,0,0}, a1=a0, a2=a0, a3=a0;
        #pragma unroll
        for (int c4=0;c4<4;++c4){
          f4v w0=wxr[0][c4], w1=wxr[1][c4], w2=wxr[2][c4], w3=wxr[3][c4];
          #pragma unroll
          for (int d=0;d<4;++d){
            int ii = kg*16 + c4*4 + d;
            f4v hv = *(const f4v*)&x_lds[ii*32 + b4*4];
            TILE_FMA(w0[d], w1[d], w2[d], w3[d], hv)
          }
        }
        REDUCE_TO_SUMS
        if (iscell){
          #pragma unroll
          for (int g=0;g<4;++g) xg[g] = bsum[g] + sums[(g*8+jloc)*32 + bl];
        }
        __syncthreads();
        if (t > 0 && tid < 512){          // Y[t-1] from h_lds (= st(t-1)); jg==0 writes
          int nc = tid>>5, b2 = tid&31;
          float y = 0.f;
          const f4v* dr = (const f4v*)(dw + nc*512);
          #pragma unroll 4
          for (int k4=0;k4<128;++k4){
            f4v dv = dr[k4];
            y = fmaf(dv.x, h_lds[(k4*4+0)*32 + b2], y);
            y = fmaf(dv.y, h_lds[(k4*4+1)*32 + b2], y);
            y = fmaf(dv.z, h_lds[(k4*4+2)*32 + b2], y);
            y = fmaf(dv.w, h_lds[(k4*4+3)*32 + b2], y);
          }
          if (jg == 0) out[((bgr*32+b2)*NCc + nc)*Tc + (t-1)] = y + db[nc];
        }
      }

      // ---- h-GEMV ----
      {
        f4v a0={0,0,0,0}, a1=a0, a2=a0, a3=a0;
        if (do_h){
          #pragma unroll
          for (int c8=0;c8<8;++c8){
            f4v w0=whr[0][c8], w1=whr[1][c8], w2=whr[2][c8], w3=whr[3][c8];
            #pragma unroll
            for (int d=0;d<4;++d){
              int k = kg*32 + c8*4 + d;
              f4v hv = *(const f4v*)&h_lds[k*32 + b4*4];
              TILE_FMA(w0[d], w1[d], w2[d], w3[d], hv)
            }
          }
        }
        REDUCE_TO_SUMS
      }

      // ---- LSTM cell (i,f,g,o) ----
      float hn=0.f, cn=0.f;
      {
        const int par = gt & 1;
        if (iscell){
          float g0 = xg[0] + sums[(0*8+jloc)*32 + bl];
          float g1 = xg[1] + sums[(1*8+jloc)*32 + bl];
          float g2 = xg[2] + sums[(2*8+jloc)*32 + bl];
          float g3 = xg[3] + sums[(3*8+jloc)*32 + bl];
          float ig = sigm(g0), fg = sigm(g1), gg = tanhf(g2), og = sigm(g3);
          cn = fg*c + ig*gg;
          hn = og*tanhf(cn);
          gstore(hbuf + par*HSZ + jglob*128 + bglob, hn);
          gstore(stc  + par*HSZ + jglob*128 + bglob, st_run + (1.f - prev_pm)*hn);
          hp[jloc*32 + bl] = hn * hwj;
        }
        __syncthreads();
        if (tid < 32){
          float s = 0.f;
          #pragma unroll
          for (int jl=0;jl<8;++jl) s += hp[jl*32 + tid];
          gstore(hpp + par*HPSZ + jg*128 + bgr*32 + tid, s);
        }
      }

      gsync(w);

      // ---- phase B: replicated halting decision (vectorized hpp read) ----
      {
        const float* hpb = hpp + (gt&1)*HPSZ;
        f4v q0 = *(const volatile f4v*)(hpb + tid*8);
        f4v q1 = *(const volatile f4v*)(hpb + tid*8 + 4);
        *(f4v*)&hq[tid*8]     = q0;
        *(f4v*)&hq[tid*8 + 4] = q1;
      }
      __syncthreads();
      if (tid < 512){
        int q4 = tid >> 7, b2 = tid & 127;
        float s = 0.f;
        for (int j2 = q4*16; j2 < q4*16+16; ++j2) s += hq[j2*128 + b2];
        hq2[q4*128 + b2] = s;
      }
      __syncthreads();
      if (tid < 128)
        pnl[tid] = (hq2[tid] + hq2[128+tid]) + (hq2[256+tid] + hq2[384+tid]);
      __syncthreads();
      if (wid < 2){
        int btr = wid*64 + lane;
        float pn = sigm(pnl[btr] + hb0);
        cumw += pn;
        int ok = __all(cumw >= 0.99f) ? 1 : 0;
        if (lane == 0) ldsu[wid] = (unsigned)ok;
        pmh[btr] = fminf(1.f, cumw);
      }
      __syncthreads();
      const int finv = (((ldsu[0] & ldsu[1]) != 0u) || (mm == Mc-1)) ? 1 : 0;

      if (wid < 2){
        float pmf = finv ? 1.f : fminf(1.f, cumw);
        if (!ntsetw && pmf >= 1.f){
          ntfw = (float)mm;
          rtvw = (mm == 0) ? 0.f : (1.f - prevw);
          ntsetw = true;
        }
        prevw = pmf;
      }
      if (iscell){
        float pm = finv ? 1.f : pmh[bglob];
        float ph = pm - prev_pm;
        st_run += ph*hn;
        ct_run += ph*cn;
        prev_pm = pm;
        c = finv ? ct_run : cn;
      }
      if (finv){
        if (w == 0 && wid < 2) out[N_OFF + (wid*64+lane)*Tc + t] = ntfw;
        if (wid < 2){
          psumw += ntfw + rtvw;
          ntsetw=false; prevw=0.f; cumw=0.f; ntfw=0.f; rtvw=0.f;
        }
        if (iscell){ st_run=0.f; ct_run=0.f; prev_pm=0.f; }
        lastpar = gt & 1;
        ++gt;
        break;
      }
      ++gt;
    }
  }

  // ---- epilogue: Y[23] from final st (stc[lastpar]); P ----
  if (jg == 0){
    const float* src = stc + lastpar*HSZ;
    #pragma unroll
    for (int u=0;u<4;++u){
      int f = u*1024 + tid, k = f>>3, q = f&7;
      f4v hv = *(const volatile f4v*)(src + k*128 + bgr*32 + q*4);
      *(f4v*)&h_lds[k*32 + q*4] = hv;
    }
    __syncthreads();
    if (tid < 512){
      int nc = tid>>5, b2 = tid&31;
      float y = 0.f;
      const f4v* dr = (const f4v*)(dw + nc*512);
      #pragma unroll 4
      for (int k4=0;k4<128;++k4){
        f4v dv = dr[k4];
        y = fmaf(dv.x, h_lds[(k4*4+0)*32 + b2], y);
        y = fmaf(dv.y, h_lds[(k4*4+1)*32 + b2], y);
        y = fmaf(dv.z, h_lds[(k4*4+2)*32 + b2], y);
        y = fmaf(dv.w, h_lds[(k4*4+3)*32 + b2], y);
      }
      out[((bgr*32+b2)*NCc + nc)*Tc + (Tc-1)] = y + db[nc];
    }
  }
  if (w == 1 && wid < 2) out[P_OFF + wid*64 + lane] = psumw;
}

extern "C" void kernel_launch(void* const* d_in, const int* in_sizes, int n_in,
                              void* d_out, int out_size, void* d_ws, size_t ws_size,
                              hipStream_t stream) {
  const float* x   = (const float*)d_in[0];
  const float* Wih = (const float*)d_in[1];
  const float* Whh = (const float*)d_in[2];
  const float* bih = (const float*)d_in[3];
  const float* bhh = (const float*)d_in[4];
  const float* hw  = (const float*)d_in[5];
  const float* hb  = (const float*)d_in[6];
  const float* dwp = (const float*)d_in[7];
  const float* dbp = (const float*)d_in[8];
  float* out = (float*)d_out;
  float* ws  = (float*)d_ws;

  void* kargs[] = {(void*)&x, (void*)&Wih, (void*)&Whh, (void*)&bih, (void*)&bhh,
                   (void*)&hw, (void*)&hb, (void*)&dwp, (void*)&dbp, (void*)&out, (void*)&ws};
  hipLaunchCooperativeKernel((void*)act_lstm_kernel, dim3(NWG), dim3(TPB),
                             kargs, 0, stream);
}

// Round 13
// 1998.067 us; speedup vs baseline: 1.1792x; 1.1792x over previous
//
#include <hip/hip_runtime.h>
#include <math.h>

#define NWG 256
#define TPB 1024

static constexpr int Bc=128, Ic=256, Hc=512, NCc=16, Tc=24, Mc=14;
static constexpr int Y_SZ  = Bc*NCc*Tc;     // 49152
static constexpr int P_OFF = Y_SZ;          // 49152
static constexpr int N_OFF = Y_SZ + Bc;     // 49280

// ws layout (floats) -- total 331776 floats = 1.27 MiB (< 1.375 proven)
static constexpr int HSZ    = Hc*Bc;                  // 65536
static constexpr int HB_OFF = 0;                      // hbuf[2][512][128]
static constexpr int SC_OFF = 2*HSZ;                  // stc[2][512][128]
static constexpr int HP_OFF = 4*HSZ;                  // hpp[2][16][128]
static constexpr int DP_OFF = HP_OFF + 2*2048;        // decp[2][16][16][128]

typedef float f4v __attribute__((ext_vector_type(4)));

// Hierarchical barrier: 16 groups x 16 blocks; monotonic watermarks, 64B lines.
__device__ __align__(64) unsigned g_bcnt[16][16];
__device__ __align__(64) unsigned g_bgen[16][16];
__device__ __align__(64) unsigned g_brc[16];
__device__ __align__(64) unsigned g_brg[16];

__device__ __forceinline__ float sigm(float v){ return 1.0f/(1.0f+expf(-v)); }

// PRODUCER: system-scope write-through stores (sc0 sc1) -> coherent at IF.
__device__ __forceinline__ void gstore(float* p, float v){
  __hip_atomic_store(p, v, __ATOMIC_RELAXED, __HIP_MEMORY_SCOPE_SYSTEM);
}
// CONSUMER: volatile loads -> sc0 sc1, bypass L1/XCD-L2, coherent at IF.
// NOTE (r11/r12 ablation): each volatile op is followed by a waitcnt, so
// chains of scalar volatile loads SERIALIZE at ~full IF latency each. Keep
// volatile-load count per critical path minimal and always f4-wide.
__device__ __forceinline__ float gload(const float* p){
  return *(const volatile float*)p;
}

__device__ __forceinline__ void gsync(int w){
  __syncthreads();
  if (threadIdx.x == 0) {
    asm volatile("" ::: "memory");
    const int g = w >> 4;                    // 16 groups of 16
    unsigned prev = __hip_atomic_fetch_add(&g_bcnt[g][0], 1u, __ATOMIC_RELAXED, __HIP_MEMORY_SCOPE_SYSTEM);
    unsigned ep   = prev >> 4;
    if ((prev & 15u) == 15u) {
      unsigned rprev = __hip_atomic_fetch_add(&g_brc[0], 1u, __ATOMIC_RELAXED, __HIP_MEMORY_SCOPE_SYSTEM);
      if ((rprev & 15u) == 15u) {
        __hip_atomic_store(&g_brg[0], (rprev >> 4) + 1u, __ATOMIC_RELEASE, __HIP_MEMORY_SCOPE_SYSTEM);
      } else {
        while ((int)(__hip_atomic_load(&g_brg[0], __ATOMIC_RELAXED, __HIP_MEMORY_SCOPE_SYSTEM) - (ep + 1u)) < 0)
          __builtin_amdgcn_s_sleep(1);
      }
      __hip_atomic_store(&g_bgen[g][0], ep + 1u, __ATOMIC_RELEASE, __HIP_MEMORY_SCOPE_SYSTEM);
    } else {
      while ((int)(__hip_atomic_load(&g_bgen[g][0], __ATOMIC_RELAXED, __HIP_MEMORY_SCOPE_SYSTEM) - (ep + 1u)) < 0)
        __builtin_amdgcn_s_sleep(1);
    }
    asm volatile("" ::: "memory");
  }
  __syncthreads();
}

__global__ __launch_bounds__(TPB, 1) void act_lstm_kernel(
    const float* __restrict__ x,   const float* __restrict__ Wih,
    const float* __restrict__ Whh, const float* __restrict__ bih,
    const float* __restrict__ bhh, const float* __restrict__ hw,
    const float* __restrict__ hbp, const float* __restrict__ dw,
    const float* __restrict__ db,  float* __restrict__ out,
    float* __restrict__ ws)
{
  const int w    = blockIdx.x;
  const int tid  = threadIdx.x;
  const int lane = tid & 63;
  const int wid  = __builtin_amdgcn_readfirstlane(tid >> 6); // 0..15 = k/i-chunk
  const int bg   = w >> 4;           // batch group: b in [bg*8, bg*8+8)
  const int js   = w & 15;           // j-slice: j in [js*32, js*32+32)
  const int kg   = wid;              // wave's k-chunk (h: 32 k, x: 16 i)
  // lanes own global rows {lane, lane+64} of this block's 128 gate rows
  const int rl0  = lane, rl1 = lane + 64;
  const int grow0 = ((rl0>>5)<<9) + js*32 + (rl0&31);
  const int grow1 = ((rl1>>5)<<9) + js*32 + (rl1&31);
  // cell ownership (threads 0..255): (jloc, bl)
  const bool iscell = (tid < 256);
  const int jloc = tid >> 3, bl = tid & 7;          // valid when iscell
  const int jglob = js*32 + jloc;
  const int bglob = bg*8 + bl;

  float* hbuf = ws + HB_OFF;
  float* stc  = ws + SC_OFF;
  float* hpp  = ws + HP_OFF;
  float* decp = ws + DP_OFF;

  __shared__ float h_lds[4096];       // [j 512][b 8]
  __shared__ float x_lds[2048];       // [i 256][b 8]
  __shared__ float part[128*129];     // [row][kg*8+b], stride 129
  __shared__ float sums[1024];        // [row*8+b]
  __shared__ float dp[4096];          // [nc 16][jloc 32][b 8]
  __shared__ float hp[256];
  __shared__ float pmh[128];
  __shared__ float hq[2048];          // staged hpp (phase B)
  __shared__ float pnl[128];
  __shared__ float dy[2048];          // staged decp (pend-Y)
  __shared__ unsigned ldsu[2];

  const f4v* Wh0 = (const f4v*)(Whh + grow0*Hc) + kg*8;  // 8 f4 (32 k)
  const f4v* Wh1 = (const f4v*)(Whh + grow1*Hc) + kg*8;
  const f4v* Wx0 = (const f4v*)(Wih + grow0*Ic) + kg*4;  // 4 f4 (16 i)
  const f4v* Wx1 = (const f4v*)(Wih + grow1*Ic) + kg*4;

  float bsum[4] = {0,0,0,0};
  float hwj = 0.f;
  if (iscell) {
    #pragma unroll
    for (int g=0; g<4; ++g) bsum[g] = bih[g*512 + jglob] + bhh[g*512 + jglob];
    hwj = hw[jglob];
  }
  const float hb0 = hbp[0];

  // persistent state
  float c = 0.f, st_run = 0.f, ct_run = 0.f, prev_pm = 0.f;          // cell
  float cumw=0.f, prevw=0.f, ntfw=0.f, rtvw=0.f, psumw=0.f;          // tracker (wid<2)
  bool  ntsetw = false;
  int   gt = 0, lastpar = 0, pend_t = -1, pend_par = 0;
  float xg[4] = {0,0,0,0};

  for (int t = 0; t < Tc; ++t) {
    for (int mm = 0;; ++mm) {
      const bool do_h = !(mm == 0 && t == 0);
      float xv0 = 0.f, xv1 = 0.f;
      if (mm == 0) {
        const int i0 = tid >> 3, b0 = tid & 7;
        const int xb = (bg*8 + b0) * (Ic*Tc);
        xv0 = x[xb + i0*Tc + t];
        xv1 = x[xb + (i0+128)*Tc + t];
      }
      // ---- load h slice (one volatile float4 per thread) ----
      if (do_h) {
        const float* src = (mm == 0) ? (stc + lastpar*HSZ) : (hbuf + ((gt-1)&1)*HSZ);
        const int j = tid >> 1, q = tid & 1;
        f4v hv = *(const volatile f4v*)(src + j*128 + bg*8 + q*4);
        *(f4v*)&h_lds[tid*4] = hv;
      }
      __syncthreads();

      if (mm == 0) {
        x_lds[tid]        = xv0;       // layout [i*8+b] == tid
        x_lds[tid + 1024] = xv1;
        __syncthreads();
        // ---- x-GEMV: rows {rl0,rl1} x i-chunk 16 x 8 b ----
        float a0[8] = {0,0,0,0,0,0,0,0}, a1[8] = {0,0,0,0,0,0,0,0};
        #pragma unroll
        for (int c4 = 0; c4 < 4; ++c4) {
          f4v w0 = Wx0[c4], w1 = Wx1[c4];
          #pragma unroll
          for (int d = 0; d < 4; ++d) {
            const float wa = w0[d], wb = w1[d];
            const float* hbp_ = &x_lds[(kg*16 + c4*4 + d)*8];
            f4v hA = *(const f4v*)hbp_, hB = *(const f4v*)(hbp_+4);
            a0[0]=fmaf(wa,hA.x,a0[0]); a0[1]=fmaf(wa,hA.y,a0[1]);
            a0[2]=fmaf(wa,hA.z,a0[2]); a0[3]=fmaf(wa,hA.w,a0[3]);
            a0[4]=fmaf(wa,hB.x,a0[4]); a0[5]=fmaf(wa,hB.y,a0[5]);
            a0[6]=fmaf(wa,hB.z,a0[6]); a0[7]=fmaf(wa,hB.w,a0[7]);
            a1[0]=fmaf(wb,hA.x,a1[0]); a1[1]=fmaf(wb,hA.y,a1[1]);
            a1[2]=fmaf(wb,hA.z,a1[2]); a1[3]=fmaf(wb,hA.w,a1[3]);
            a1[4]=fmaf(wb,hB.x,a1[4]); a1[5]=fmaf(wb,hB.y,a1[5]);
            a1[6]=fmaf(wb,hB.z,a1[6]); a1[7]=fmaf(wb,hB.w,a1[7]);
          }
        }
        #pragma unroll
        for (int b = 0; b < 8; ++b) {
          part[rl0*129 + kg*8 + b] = a0[b];
          part[rl1*129 + kg*8 + b] = a1[b];
        }
        __syncthreads();
        { // stage1 reduce over kg
          const int row = tid >> 3, b = tid & 7;
          float s = 0.f;
          #pragma unroll
          for (int q2 = 0; q2 < 16; ++q2) s += part[row*129 + q2*8 + b];
          sums[tid] = s;
        }
        __syncthreads();
        if (iscell) {
          #pragma unroll
          for (int g = 0; g < 4; ++g) xg[g] = bsum[g] + sums[(g*32 + jloc)*8 + bl];
        }
        __syncthreads();   // part/sums free for h round
      }

      // ---- h-GEMV: rows {rl0,rl1} x k-chunk 32 x 8 b ----
      {
        float a0[8] = {0,0,0,0,0,0,0,0}, a1[8] = {0,0,0,0,0,0,0,0};
        if (do_h) {
          #pragma unroll
          for (int c4 = 0; c4 < 8; ++c4) {
            f4v w0 = Wh0[c4], w1 = Wh1[c4];
            #pragma unroll
            for (int d = 0; d < 4; ++d) {
              const float wa = w0[d], wb = w1[d];
              const float* hbp_ = &h_lds[(kg*32 + c4*4 + d)*8];
              f4v hA = *(const f4v*)hbp_, hB = *(const f4v*)(hbp_+4);
              a0[0]=fmaf(wa,hA.x,a0[0]); a0[1]=fmaf(wa,hA.y,a0[1]);
              a0[2]=fmaf(wa,hA.z,a0[2]); a0[3]=fmaf(wa,hA.w,a0[3]);
              a0[4]=fmaf(wa,hB.x,a0[4]); a0[5]=fmaf(wa,hB.y,a0[5]);
              a0[6]=fmaf(wa,hB.z,a0[6]); a0[7]=fmaf(wa,hB.w,a0[7]);
              a1[0]=fmaf(wb,hA.x,a1[0]); a1[1]=fmaf(wb,hA.y,a1[1]);
              a1[2]=fmaf(wb,hA.z,a1[2]); a1[3]=fmaf(wb,hA.w,a1[3]);
              a1[4]=fmaf(wb,hB.x,a1[4]); a1[5]=fmaf(wb,hB.y,a1[5]);
              a1[6]=fmaf(wb,hB.z,a1[6]); a1[7]=fmaf(wb,hB.w,a1[7]);
            }
          }
        }
        #pragma unroll
        for (int b = 0; b < 8; ++b) {
          part[rl0*129 + kg*8 + b] = a0[b];
          part[rl1*129 + kg*8 + b] = a1[b];
        }
      }
      __syncthreads();
      {
        const int row = tid >> 3, b = tid & 7;
        float s = 0.f;
        #pragma unroll
        for (int q2 = 0; q2 < 16; ++q2) s += part[row*129 + q2*8 + b];
        sums[tid] = s;
      }
      __syncthreads();

      // ---- LSTM cell (i,f,g,o) ----
      float hn = 0.f, cn = 0.f;
      if (iscell) {
        float g0 = xg[0] + sums[(0*32 + jloc)*8 + bl];
        float g1 = xg[1] + sums[(1*32 + jloc)*8 + bl];
        float g2 = xg[2] + sums[(2*32 + jloc)*8 + bl];
        float g3 = xg[3] + sums[(3*32 + jloc)*8 + bl];
        float ig = sigm(g0), fg = sigm(g1), gg = tanhf(g2), og = sigm(g3);
        cn = fg*c + ig*gg;
        hn = og*tanhf(cn);
        const int par = gt & 1;
        gstore(hbuf + par*HSZ + jglob*128 + bglob, hn);
        gstore(stc  + par*HSZ + jglob*128 + bglob, st_run + (1.f - prev_pm)*hn);
        hp[tid] = hn * hwj;
      }
      __syncthreads();
      if (tid < 8) {
        float s = 0.f;
        #pragma unroll
        for (int jl = 0; jl < 32; ++jl) s += hp[jl*8 + tid];
        gstore(hpp + (gt&1)*2048 + js*128 + bg*8 + tid, s);
      }

      gsync(w);

      // ---- phase B ----
      if (pend_t >= 0) {            // Y for previous timestep (decp visible now)
        if (js == 0) {
          if (tid < 512) {          // stage decp: one volatile f4 per thread
            const int js2 = tid >> 5, nc = (tid >> 1) & 15, hf = tid & 1;
            f4v v = *(const volatile f4v*)(decp + pend_par*32768 + js2*2048 + nc*128 + bg*8 + hf*4);
            *(f4v*)&dy[js2*128 + nc*8 + hf*4] = v;
          }
          __syncthreads();
          if (tid < 128) {
            const int nc = tid >> 3, b2 = tid & 7;
            float y = 0.f;
            #pragma unroll
            for (int js2 = 0; js2 < 16; ++js2) y += dy[js2*128 + nc*8 + b2];
            out[((bg*8 + b2)*NCc + nc)*Tc + pend_t] = y + db[nc];
          }
        }
        pend_t = -1;
      }
      const int par = gt & 1;
      // halt decision: stage hpp with 512 x one volatile f4 -> LDS tree
      if (tid < 512) {
        f4v v = *(const volatile f4v*)(hpp + par*2048 + tid*4);
        *(f4v*)&hq[tid*4] = v;
      }
      __syncthreads();
      if (tid < 128) {
        float s = 0.f;
        #pragma unroll
        for (int js2 = 0; js2 < 16; ++js2) s += hq[js2*128 + tid];
        pnl[tid] = s;
      }
      __syncthreads();
      if (wid < 2) {
        const int b2 = wid*64 + lane;
        float pn = sigm(pnl[b2] + hb0);
        cumw += pn;
        int ok = __all(cumw >= 0.99f) ? 1 : 0;
        if (lane == 0) ldsu[wid] = (unsigned)ok;
        pmh[b2] = fminf(1.f, cumw);
      }
      __syncthreads();
      const int finv = (((ldsu[0] & ldsu[1]) != 0u) || (mm == Mc-1)) ? 1 : 0;

      if (wid < 2) {
        float pmf = finv ? 1.f : fminf(1.f, cumw);
        if (!ntsetw && pmf >= 1.f) {
          ntfw = (float)mm;
          rtvw = (mm == 0) ? 0.f : (1.f - prevw);
          ntsetw = true;
        }
        prevw = pmf;
      }
      if (iscell) {
        float pm = finv ? 1.f : pmh[bglob];
        float ph = pm - prev_pm;
        st_run += ph*hn;
        ct_run += ph*cn;
        prev_pm = pm;
        c = finv ? ct_run : cn;
      }
      if (finv) {
        if (iscell) {
          #pragma unroll
          for (int nc = 0; nc < 16; ++nc)
            dp[nc*256 + tid] = dw[nc*512 + jglob] * st_run;
        }
        __syncthreads();
        if (tid < 128) {
          const int nc = tid >> 3, b2 = tid & 7;
          float s = 0.f;
          #pragma unroll
          for (int jl = 0; jl < 32; ++jl) s += dp[nc*256 + jl*8 + b2];
          gstore(decp + par*32768 + js*2048 + nc*128 + bg*8 + b2, s);
        }
        if (w == 0 && wid < 2)
          out[N_OFF + (wid*64 + lane)*Tc + t] = ntfw;
        if (wid < 2) {
          psumw += ntfw + rtvw;
          ntsetw = false; prevw = 0.f; cumw = 0.f; ntfw = 0.f; rtvw = 0.f;
        }
        if (iscell) { st_run = 0.f; ct_run = 0.f; prev_pm = 0.f; }
        pend_t = t; pend_par = par; lastpar = par;
      }
      ++gt;
      if (finv) break;
    }
  }

  // ---- epilogue: Y for t=23, P ----
  gsync(w);
  if (pend_t >= 0 && js == 0) {
    if (tid < 512) {
      const int js2 = tid >> 5, nc = (tid >> 1) & 15, hf = tid & 1;
      f4v v = *(const volatile f4v*)(decp + pend_par*32768 + js2*2048 + nc*128 + bg*8 + hf*4);
      *(f4v*)&dy[js2*128 + nc*8 + hf*4] = v;
    }
    __syncthreads();
    if (tid < 128) {
      const int nc = tid >> 3, b2 = tid & 7;
      float y = 0.f;
      #pragma unroll
      for (int js2 = 0; js2 < 16; ++js2) y += dy[js2*128 + nc*8 + b2];
      out[((bg*8 + b2)*NCc + nc)*Tc + pend_t] = y + db[nc];
    }
  }
  if (w == 1 && wid < 2) out[P_OFF + wid*64 + lane] = psumw;
}

extern "C" void kernel_launch(void* const* d_in, const int* in_sizes, int n_in,
                              void* d_out, int out_size, void* d_ws, size_t ws_size,
                              hipStream_t stream) {
  const float* x   = (const float*)d_in[0];
  const float* Wih = (const float*)d_in[1];
  const float* Whh = (const float*)d_in[2];
  const float* bih = (const float*)d_in[3];
  const float* bhh = (const float*)d_in[4];
  const float* hw  = (const float*)d_in[5];
  const float* hb  = (const float*)d_in[6];
  const float* dwp = (const float*)d_in[7];
  const float* dbp = (const float*)d_in[8];
  float* out = (float*)d_out;
  float* ws  = (float*)d_ws;

  void* kargs[] = {(void*)&x, (void*)&Wih, (void*)&Whh, (void*)&bih, (void*)&bhh,
                   (void*)&hw, (void*)&hb, (void*)&dwp, (void*)&dbp, (void*)&out, (void*)&ws};
  hipLaunchCooperativeKernel((void*)act_lstm_kernel, dim3(NWG), dim3(TPB),
                             kargs, 0, stream);
}

// Round 14
// 1929.091 us; speedup vs baseline: 1.2214x; 1.0358x over previous
//
#include <hip/hip_runtime.h>
#include <math.h>

#define NWG 256
#define TPB 1024

static constexpr int Bc=128, Ic=256, Hc=512, NCc=16, Tc=24, Mc=14;
static constexpr int Y_SZ  = Bc*NCc*Tc;     // 49152
static constexpr int P_OFF = Y_SZ;          // 49152
static constexpr int N_OFF = Y_SZ + Bc;     // 49280

// ws layout (floats) -- total 331776 floats = 1.27 MiB (< 1.375 proven)
static constexpr int HSZ    = Hc*Bc;                  // 65536
static constexpr int HB_OFF = 0;                      // hbuf[2][512][128]
static constexpr int SC_OFF = 2*HSZ;                  // stc[2][512][128]
static constexpr int HP_OFF = 4*HSZ;                  // hpp[2][16][128]
static constexpr int DP_OFF = HP_OFF + 2*2048;        // decp[2][16][16][128]

typedef float f4v __attribute__((ext_vector_type(4)));

// Hierarchical barrier: 16 groups x 16 blocks; monotonic watermarks, 64B lines.
__device__ __align__(64) unsigned g_bcnt[16][16];
__device__ __align__(64) unsigned g_bgen[16][16];
__device__ __align__(64) unsigned g_brc[16];
__device__ __align__(64) unsigned g_brg[16];

__device__ __forceinline__ float sigm(float v){ return 1.0f/(1.0f+expf(-v)); }

// PRODUCER: system-scope write-through stores (sc0 sc1) -> coherent at IF.
__device__ __forceinline__ void gstore(float* p, float v){
  __hip_atomic_store(p, v, __ATOMIC_RELAXED, __HIP_MEMORY_SCOPE_SYSTEM);
}
// CONSUMER: volatile loads -> sc0 sc1, bypass L1/XCD-L2, coherent at IF.
// Keep volatile-load count per critical path minimal, always f4-wide (r13).
__device__ __forceinline__ float gload(const float* p){
  return *(const volatile float*)p;
}

__device__ __forceinline__ void gsync(int w){
  __syncthreads();
  if (threadIdx.x == 0) {
    asm volatile("" ::: "memory");
    const int g = w >> 4;                    // 16 groups of 16
    unsigned prev = __hip_atomic_fetch_add(&g_bcnt[g][0], 1u, __ATOMIC_RELAXED, __HIP_MEMORY_SCOPE_SYSTEM);
    unsigned ep   = prev >> 4;
    if ((prev & 15u) == 15u) {
      unsigned rprev = __hip_atomic_fetch_add(&g_brc[0], 1u, __ATOMIC_RELAXED, __HIP_MEMORY_SCOPE_SYSTEM);
      if ((rprev & 15u) == 15u) {
        __hip_atomic_store(&g_brg[0], (rprev >> 4) + 1u, __ATOMIC_RELEASE, __HIP_MEMORY_SCOPE_SYSTEM);
      } else {
        while ((int)(__hip_atomic_load(&g_brg[0], __ATOMIC_RELAXED, __HIP_MEMORY_SCOPE_SYSTEM) - (ep + 1u)) < 0)
          __builtin_amdgcn_s_sleep(1);
      }
      __hip_atomic_store(&g_bgen[g][0], ep + 1u, __ATOMIC_RELEASE, __HIP_MEMORY_SCOPE_SYSTEM);
    } else {
      while ((int)(__hip_atomic_load(&g_bgen[g][0], __ATOMIC_RELAXED, __HIP_MEMORY_SCOPE_SYSTEM) - (ep + 1u)) < 0)
        __builtin_amdgcn_s_sleep(1);
    }
    asm volatile("" ::: "memory");
  }
  __syncthreads();
}

__global__ __launch_bounds__(TPB, 1) void act_lstm_kernel(
    const float* __restrict__ x,   const float* __restrict__ Wih,
    const float* __restrict__ Whh, const float* __restrict__ bih,
    const float* __restrict__ bhh, const float* __restrict__ hw,
    const float* __restrict__ hbp, const float* __restrict__ dw,
    const float* __restrict__ db,  float* __restrict__ out,
    float* __restrict__ ws)
{
  const int w    = blockIdx.x;
  const int tid  = threadIdx.x;
  const int lane = tid & 63;
  const int wid  = __builtin_amdgcn_readfirstlane(tid >> 6); // 0..15 = k/i-chunk
  // XCD-aware slice swizzle: assume blockIdx round-robins XCDs (%8).
  // Blocks on one XCD then share only 2 distinct js weight slices
  // (768 KB/XCD << 4 MB L2 -> weights L2-resident). Bijective remap.
  const int xcg  = w & 7, xidx = w >> 3;
  const int js   = (xcg << 1) | (xidx & 1);   // j-slice [0,16)
  const int bg   = xidx >> 1;                 // batch group [0,16)
  const int kg   = wid;              // wave's k-chunk (h: 32 k, x: 16 i)
  const int rl0  = lane, rl1 = lane + 64;
  const int grow0 = ((rl0>>5)<<9) + js*32 + (rl0&31);
  const int grow1 = ((rl1>>5)<<9) + js*32 + (rl1&31);
  const bool iscell = (tid < 256);
  const int jloc = tid >> 3, bl = tid & 7;
  const int jglob = js*32 + jloc;
  const int bglob = bg*8 + bl;

  float* hbuf = ws + HB_OFF;
  float* stc  = ws + SC_OFF;
  float* hpp  = ws + HP_OFF;
  float* decp = ws + DP_OFF;

  __shared__ float h_lds[4096];       // [j 512][b 8]
  __shared__ float x_lds[2048];       // [i 256][b 8]
  __shared__ float part[128*129];     // [row][kg*8+b], stride 129
  __shared__ float sums[1024];        // [row*8+b]
  __shared__ float dp[4096];          // [nc 16][jloc 32][b 8]
  __shared__ float hp[256];
  __shared__ float pmh[128];
  __shared__ float hq[2048];          // staged hpp (phase B)
  __shared__ float pnl[128];
  __shared__ float dy[128];           // staged decp for nc=js (pend-Y)
  __shared__ unsigned ldsu[2];

  const f4v* Wh0 = (const f4v*)(Whh + grow0*Hc) + kg*8;  // 8 f4 (32 k)
  const f4v* Wh1 = (const f4v*)(Whh + grow1*Hc) + kg*8;
  const f4v* Wx0 = (const f4v*)(Wih + grow0*Ic) + kg*4;  // 4 f4 (16 i)
  const f4v* Wx1 = (const f4v*)(Wih + grow1*Ic) + kg*4;

  float bsum[4] = {0,0,0,0};
  float hwj = 0.f;
  if (iscell) {
    #pragma unroll
    for (int g=0; g<4; ++g) bsum[g] = bih[g*512 + jglob] + bhh[g*512 + jglob];
    hwj = hw[jglob];
  }
  const float hb0 = hbp[0];

  // persistent state
  float c = 0.f, st_run = 0.f, ct_run = 0.f, prev_pm = 0.f;          // cell
  float cumw=0.f, prevw=0.f, ntfw=0.f, rtvw=0.f, psumw=0.f;          // tracker (wid<2)
  bool  ntsetw = false;
  int   gt = 0, lastpar = 0, pend_t = -1, pend_par = 0;
  float xg[4] = {0,0,0,0};
  f4v   spec = {0,0,0,0};             // speculative next-tick h (continue path)
  bool  have_spec = false;

  for (int t = 0; t < Tc; ++t) {
    for (int mm = 0;; ++mm) {
      const bool do_h = !(mm == 0 && t == 0);
      float xv0 = 0.f, xv1 = 0.f;
      if (mm == 0) {
        const int i0 = tid >> 3, b0 = tid & 7;
        const int xb = (bg*8 + b0) * (Ic*Tc);
        xv0 = x[xb + i0*Tc + t];
        xv1 = x[xb + (i0+128)*Tc + t];
      }
      // ---- h slice into LDS: speculative reg (mm>0) or volatile f4 load ----
      if (do_h) {
        if (mm > 0 && have_spec) {
          *(f4v*)&h_lds[tid*4] = spec;     // prefetched during last phase B
        } else {
          const float* src = (mm == 0) ? (stc + lastpar*HSZ) : (hbuf + ((gt-1)&1)*HSZ);
          const int j = tid >> 1, q = tid & 1;
          f4v hv = *(const volatile f4v*)(src + j*128 + bg*8 + q*4);
          *(f4v*)&h_lds[tid*4] = hv;
        }
      }
      __syncthreads();

      if (mm == 0) {
        x_lds[tid]        = xv0;       // layout [i*8+b] == tid
        x_lds[tid + 1024] = xv1;
        __syncthreads();
        // ---- x-GEMV: rows {rl0,rl1} x i-chunk 16 x 8 b ----
        float a0[8] = {0,0,0,0,0,0,0,0}, a1[8] = {0,0,0,0,0,0,0,0};
        #pragma unroll
        for (int c4 = 0; c4 < 4; ++c4) {
          f4v w0 = Wx0[c4], w1 = Wx1[c4];
          #pragma unroll
          for (int d = 0; d < 4; ++d) {
            const float wa = w0[d], wb = w1[d];
            const float* hbp_ = &x_lds[(kg*16 + c4*4 + d)*8];
            f4v hA = *(const f4v*)hbp_, hB = *(const f4v*)(hbp_+4);
            a0[0]=fmaf(wa,hA.x,a0[0]); a0[1]=fmaf(wa,hA.y,a0[1]);
            a0[2]=fmaf(wa,hA.z,a0[2]); a0[3]=fmaf(wa,hA.w,a0[3]);
            a0[4]=fmaf(wa,hB.x,a0[4]); a0[5]=fmaf(wa,hB.y,a0[5]);
            a0[6]=fmaf(wa,hB.z,a0[6]); a0[7]=fmaf(wa,hB.w,a0[7]);
            a1[0]=fmaf(wb,hA.x,a1[0]); a1[1]=fmaf(wb,hA.y,a1[1]);
            a1[2]=fmaf(wb,hA.z,a1[2]); a1[3]=fmaf(wb,hA.w,a1[3]);
            a1[4]=fmaf(wb,hB.x,a1[4]); a1[5]=fmaf(wb,hB.y,a1[5]);
            a1[6]=fmaf(wb,hB.z,a1[6]); a1[7]=fmaf(wb,hB.w,a1[7]);
          }
        }
        #pragma unroll
        for (int b = 0; b < 8; ++b) {
          part[rl0*129 + kg*8 + b] = a0[b];
          part[rl1*129 + kg*8 + b] = a1[b];
        }
        __syncthreads();
        {
          const int row = tid >> 3, b = tid & 7;
          float s = 0.f;
          #pragma unroll
          for (int q2 = 0; q2 < 16; ++q2) s += part[row*129 + q2*8 + b];
          sums[tid] = s;
        }
        __syncthreads();
        if (iscell) {
          #pragma unroll
          for (int g = 0; g < 4; ++g) xg[g] = bsum[g] + sums[(g*32 + jloc)*8 + bl];
        }
        __syncthreads();
      }

      // ---- h-GEMV: rows {rl0,rl1} x k-chunk 32 x 8 b ----
      {
        float a0[8] = {0,0,0,0,0,0,0,0}, a1[8] = {0,0,0,0,0,0,0,0};
        if (do_h) {
          #pragma unroll
          for (int c4 = 0; c4 < 8; ++c4) {
            f4v w0 = Wh0[c4], w1 = Wh1[c4];
            #pragma unroll
            for (int d = 0; d < 4; ++d) {
              const float wa = w0[d], wb = w1[d];
              const float* hbp_ = &h_lds[(kg*32 + c4*4 + d)*8];
              f4v hA = *(const f4v*)hbp_, hB = *(const f4v*)(hbp_+4);
              a0[0]=fmaf(wa,hA.x,a0[0]); a0[1]=fmaf(wa,hA.y,a0[1]);
              a0[2]=fmaf(wa,hA.z,a0[2]); a0[3]=fmaf(wa,hA.w,a0[3]);
              a0[4]=fmaf(wa,hB.x,a0[4]); a0[5]=fmaf(wa,hB.y,a0[5]);
              a0[6]=fmaf(wa,hB.z,a0[6]); a0[7]=fmaf(wa,hB.w,a0[7]);
              a1[0]=fmaf(wb,hA.x,a1[0]); a1[1]=fmaf(wb,hA.y,a1[1]);
              a1[2]=fmaf(wb,hA.z,a1[2]); a1[3]=fmaf(wb,hA.w,a1[3]);
              a1[4]=fmaf(wb,hB.x,a1[4]); a1[5]=fmaf(wb,hB.y,a1[5]);
              a1[6]=fmaf(wb,hB.z,a1[6]); a1[7]=fmaf(wb,hB.w,a1[7]);
            }
          }
        }
        #pragma unroll
        for (int b = 0; b < 8; ++b) {
          part[rl0*129 + kg*8 + b] = a0[b];
          part[rl1*129 + kg*8 + b] = a1[b];
        }
      }
      __syncthreads();
      {
        const int row = tid >> 3, b = tid & 7;
        float s = 0.f;
        #pragma unroll
        for (int q2 = 0; q2 < 16; ++q2) s += part[row*129 + q2*8 + b];
        sums[tid] = s;
      }
      __syncthreads();

      // ---- LSTM cell (i,f,g,o) ----
      float hn = 0.f, cn = 0.f;
      if (iscell) {
        float g0 = xg[0] + sums[(0*32 + jloc)*8 + bl];
        float g1 = xg[1] + sums[(1*32 + jloc)*8 + bl];
        float g2 = xg[2] + sums[(2*32 + jloc)*8 + bl];
        float g3 = xg[3] + sums[(3*32 + jloc)*8 + bl];
        float ig = sigm(g0), fg = sigm(g1), gg = tanhf(g2), og = sigm(g3);
        cn = fg*c + ig*gg;
        hn = og*tanhf(cn);
        const int par = gt & 1;
        gstore(hbuf + par*HSZ + jglob*128 + bglob, hn);
        gstore(stc  + par*HSZ + jglob*128 + bglob, st_run + (1.f - prev_pm)*hn);
        hp[tid] = hn * hwj;
      }
      __syncthreads();
      if (tid < 8) {
        float s = 0.f;
        #pragma unroll
        for (int jl = 0; jl < 32; ++jl) s += hp[jl*8 + tid];
        gstore(hpp + (gt&1)*2048 + js*128 + bg*8 + tid, s);
      }

      gsync(w);

      // ---- phase B ----
      const int par = gt & 1;
      // speculative prefetch of next tick's continue-path h (hbuf[par])
      {
        const int j = tid >> 1, q = tid & 1;
        spec = *(const volatile f4v*)(hbuf + par*HSZ + j*128 + bg*8 + q*4);
        have_spec = true;
      }
      // halt staging (tid<512) and pend-Y decp staging (tids 512..543) in parallel
      if (tid < 512) {
        f4v v = *(const volatile f4v*)(hpp + par*2048 + tid*4);
        *(f4v*)&hq[tid*4] = v;
      } else if (pend_t >= 0 && tid < 544) {
        const int js2 = (tid - 512) >> 1, hf = tid & 1;
        f4v v = *(const volatile f4v*)(decp + pend_par*32768 + js2*2048 + js*128 + bg*8 + hf*4);
        *(f4v*)&dy[js2*8 + hf*4] = v;
      }
      __syncthreads();
      if (tid < 128) {
        float s = 0.f;
        #pragma unroll
        for (int js2 = 0; js2 < 16; ++js2) s += hq[js2*128 + tid];
        pnl[tid] = s;
      } else if (pend_t >= 0 && tid >= 256 && tid < 264) {
        const int b2 = tid - 256;
        float y = 0.f;
        #pragma unroll
        for (int js2 = 0; js2 < 16; ++js2) y += dy[js2*8 + b2];
        out[((bg*8 + b2)*NCc + js)*Tc + pend_t] = y + db[js];
      }
      if (pend_t >= 0 && tid == 0) ; // (pend cleared below uniformly)
      __syncthreads();
      pend_t = -1;
      if (wid < 2) {
        const int b2 = wid*64 + lane;
        float pn = sigm(pnl[b2] + hb0);
        cumw += pn;
        int ok = __all(cumw >= 0.99f) ? 1 : 0;
        if (lane == 0) ldsu[wid] = (unsigned)ok;
        pmh[b2] = fminf(1.f, cumw);
      }
      __syncthreads();
      const int finv = (((ldsu[0] & ldsu[1]) != 0u) || (mm == Mc-1)) ? 1 : 0;

      if (wid < 2) {
        float pmf = finv ? 1.f : fminf(1.f, cumw);
        if (!ntsetw && pmf >= 1.f) {
          ntfw = (float)mm;
          rtvw = (mm == 0) ? 0.f : (1.f - prevw);
          ntsetw = true;
        }
        prevw = pmf;
      }
      if (iscell) {
        float pm = finv ? 1.f : pmh[bglob];
        float ph = pm - prev_pm;
        st_run += ph*hn;
        ct_run += ph*cn;
        prev_pm = pm;
        c = finv ? ct_run : cn;
      }
      if (finv) {
        if (iscell) {
          #pragma unroll
          for (int nc = 0; nc < 16; ++nc)
            dp[nc*256 + tid] = dw[nc*512 + jglob] * st_run;
        }
        __syncthreads();
        if (tid < 128) {
          const int nc = tid >> 3, b2 = tid & 7;
          float s = 0.f;
          #pragma unroll
          for (int jl = 0; jl < 32; ++jl) s += dp[nc*256 + jl*8 + b2];
          gstore(decp + par*32768 + js*2048 + nc*128 + bg*8 + b2, s);
        }
        if (bg == 0 && js == 0 && wid < 2)
          out[N_OFF + (wid*64 + lane)*Tc + t] = ntfw;
        if (wid < 2) {
          psumw += ntfw + rtvw;
          ntsetw = false; prevw = 0.f; cumw = 0.f; ntfw = 0.f; rtvw = 0.f;
        }
        if (iscell) { st_run = 0.f; ct_run = 0.f; prev_pm = 0.f; }
        pend_t = t; pend_par = par; lastpar = par;
      }
      ++gt;
      if (finv) break;
    }
  }

  // ---- epilogue: Y for t=23 (distributed, nc=js), P ----
  gsync(w);
  if (pend_t >= 0) {
    if (tid < 32) {
      const int js2 = tid >> 1, hf = tid & 1;
      f4v v = *(const volatile f4v*)(decp + pend_par*32768 + js2*2048 + js*128 + bg*8 + hf*4);
      *(f4v*)&dy[js2*8 + hf*4] = v;
    }
    __syncthreads();
    if (tid < 8) {
      float y = 0.f;
      #pragma unroll
      for (int js2 = 0; js2 < 16; ++js2) y += dy[js2*8 + tid];
      out[((bg*8 + tid)*NCc + js)*Tc + pend_t] = y + db[js];
    }
  }
  if (bg == 0 && js == 1 && wid < 2) out[P_OFF + wid*64 + lane] = psumw;
}

extern "C" void kernel_launch(void* const* d_in, const int* in_sizes, int n_in,
                              void* d_out, int out_size, void* d_ws, size_t ws_size,
                              hipStream_t stream) {
  const float* x   = (const float*)d_in[0];
  const float* Wih = (const float*)d_in[1];
  const float* Whh = (const float*)d_in[2];
  const float* bih = (const float*)d_in[3];
  const float* bhh = (const float*)d_in[4];
  const float* hw  = (const float*)d_in[5];
  const float* hb  = (const float*)d_in[6];
  const float* dwp = (const float*)d_in[7];
  const float* dbp = (const float*)d_in[8];
  float* out = (float*)d_out;
  float* ws  = (float*)d_ws;

  void* kargs[] = {(void*)&x, (void*)&Wih, (void*)&Whh, (void*)&bih, (void*)&bhh,
                   (void*)&hw, (void*)&hb, (void*)&dwp, (void*)&dbp, (void*)&out, (void*)&ws};
  hipLaunchCooperativeKernel((void*)act_lstm_kernel, dim3(NWG), dim3(TPB),
                             kargs, 0, stream);
}